// Round 10
// baseline (242.314 us; speedup 1.0000x reference)
//
#include <hip/hip_runtime.h>
#include <stdint.h>

typedef unsigned short u16;
typedef __bf16 bf16x8 __attribute__((ext_vector_type(8)));
typedef float f32x4 __attribute__((ext_vector_type(4)));
typedef float f32x2 __attribute__((ext_vector_type(2)));
typedef u16 u16x4v __attribute__((ext_vector_type(4)));

#define DI __device__ __forceinline__

constexpr int BB = 2, SS = 2048, EE = 1024, HH = 16, DD = 64;
constexpr int MROWS = BB * SS;   // 4096 tokens
constexpr int KDIM = 1024, NDIM = 1024;

constexpr float FM = 12.0f;      // fixed max offset (log2 domain)
constexpr float MNEG = -30000.f;

DI u16 f2bf(float f) {  // RNE float->bf16 (finite inputs)
  uint32_t u = __float_as_uint(f);
  return (u16)((u + 0x7FFFu + ((u >> 16) & 1u)) >> 16);
}

DI uint32_t cvtpk_bf16(float a, float b) {  // low=bf16(a), high=bf16(b), RNE
  uint32_t r;
  asm("v_cvt_pk_bf16_f32 %0, %1, %2" : "=v"(r) : "v"(a), "v"(b));
  return r;
}

DI void cp16(const void* g, void* lds) {
  __builtin_amdgcn_global_load_lds((const __attribute__((address_space(1))) void*)g,
                                   (__attribute__((address_space(3))) void*)lds, 16, 0, 0);
}

DI f32x4 mfma16(bf16x8 a, bf16x8 b, f32x4 c) {
  return __builtin_amdgcn_mfma_f32_16x16x32_bf16(a, b, c, 0, 0, 0);
}

// ---------------- prep: weights fp32->bf16 + RoPE table + mask floats -------
// Input X (q/k/v) is no longer pre-cast: gemm_qkv casts it in-staging. This
// kernel is ~28MB of traffic (was ~100MB) -> ~2us.
__global__ __launch_bounds__(256) void prep_w(
    const float* __restrict__ wq, const float* __restrict__ wk,
    const float* __restrict__ wv, const float* __restrict__ wo,
    const int* __restrict__ mask,
    u16* __restrict__ wqb, u16* __restrict__ wkb, u16* __restrict__ wvb,
    u16* __restrict__ wob, float* __restrict__ csT, float* __restrict__ mfl) {
  const int t = blockIdx.x * 256 + threadIdx.x;   // < 1,048,576
  if (t < SS * 64) {   // RoPE table: csT[s][d] = {cos, sin}
    const int s = t >> 6, d = t & 63, j = d & 31;
    const float ang = (float)s * exp2f(-(float)j * 0.4152410118f);
    float2 cs; cs.x = cosf(ang); cs.y = sinf(ang);
    ((float2*)csT)[t] = cs;
    if (t < BB * SS) mfl[t] = mask[t] ? -FM : MNEG;
  }
  const size_t g = (size_t)t * 4;                 // over 4 x 1M weight elems
  const int wi = (int)(g >> 20);
  const size_t o = g & ((1u << 20) - 1);
  const float* src = wi == 0 ? wq : wi == 1 ? wk : wi == 2 ? wv : wo;
  u16* dst = wi == 0 ? wqb : wi == 1 ? wkb : wi == 2 ? wvb : wob;
  const float4 f = *(const float4*)(src + o);
  u16x4v hv;
  hv[0] = f2bf(f.x); hv[1] = f2bf(f.y); hv[2] = f2bf(f.z); hv[3] = f2bf(f.w);
  *(u16x4v*)(dst + o) = hv;
}

// ---------------- QKV projection GEMM, BK=64, dbuf, fused X-cast ------------
// W operand (bf16, from prep_w): async global_load_lds (zero-VGPR path).
// X operand (raw f32 input): reg-staged -- float4 x2 loads issued BEFORE the
// MFMA block, cvt_pk_bf16 + ds_write_b128 AFTER it (T14 async split: f32 load
// latency hides under MFMA). LDS layout/swizzles identical to the pre-cast
// version -> bit-identical numerics.
// Q/K: A = W (m=feat), B = X (n=token), RoPE in-register.
// V  : A = X (m=token), B = Wv (n=feat); Vtg keys pi-permuted in 32-groups.
__global__ __launch_bounds__(256) void gemm_qkv(
    const float* __restrict__ qf, const float* __restrict__ kf, const float* __restrict__ vf,
    const u16* __restrict__ wqb, const u16* __restrict__ wkb, const u16* __restrict__ wvb,
    const float* __restrict__ bq, const float* __restrict__ bk, const float* __restrict__ bv,
    u16* __restrict__ Qp, u16* __restrict__ Kp, u16* __restrict__ Vtg,
    const float* __restrict__ csT) {
  __shared__ alignas(16) u16 sW[2][128 * 64];
  __shared__ alignas(16) u16 sX[2][128 * 64];
  // grid = (8, 96), 768 blocks = 8 XCDs x 96. hw id % 8 = XCD.
  const int flat = blockIdx.y * 8 + blockIdx.x;
  const int swz = (flat & 7) * 96 + (flat >> 3);
  const int bx = swz & 7, by = swz >> 3;   // by in [xcd*12, xcd*12+12)

  const int tsel = by >> 5;  // 0=Q 1=K 2=V
  const bool vtr = (tsel == 2);
  const float* Xs = tsel == 0 ? qf : tsel == 1 ? kf : vf;
  const u16* Ws   = tsel == 0 ? wqb : tsel == 1 ? wkb : wvb;
  const float* bias = tsel == 0 ? bq : tsel == 1 ? bk : bv;

  const int fBase = bx * 128;          // feature block (8)
  const int tBase = (by & 31) * 128;   // token block (32)
  const int tid = threadIdx.x;
  const int lane = tid & 63, w = tid >> 6;
  const int quad = lane >> 4, l16 = lane & 15;
  const int wr = w >> 1, wc = w & 1;

  // staging: 1024 chunks of 16B(bf16)/32B(f32) per matrix; chunk c: row=c>>3,
  // slot=c&7, global k-chunk = slot ^ (row&7)  (XOR swizzle on GLOBAL side)
  size_t wSrc[4], xSrc[4];
  int dOff[4];
#pragma unroll
  for (int j = 0; j < 4; ++j) {
    const int c = tid + j * 256;
    const int row = c >> 3, sl = c & 7;
    const int g8 = (sl ^ (row & 7)) * 8;   // element index within k-window
    wSrc[j] = (size_t)(fBase + row) * KDIM + g8;
    xSrc[j] = (size_t)(tBase + row) * KDIM + g8;
    dOff[j] = c * 8;
  }

  f32x4 acc[4][4];
#pragma unroll
  for (int mi = 0; mi < 4; ++mi)
#pragma unroll
    for (int ni = 0; ni < 4; ++ni)
#pragma unroll
      for (int e = 0; e < 4; ++e) acc[mi][ni][e] = 0.f;

  const int arow = wr * 64 + l16, brow = wc * 64 + l16;

  float4 xlo[4], xhi[4];
  auto loadX = [&](int k0) {
#pragma unroll
    for (int j = 0; j < 4; ++j) {
      const float* p = Xs + xSrc[j] + k0;
      xlo[j] = *(const float4*)p;
      xhi[j] = *(const float4*)(p + 4);
    }
  };
  auto writeX = [&](int bi) {
#pragma unroll
    for (int j = 0; j < 4; ++j) {
      uint4 wv4;
      wv4.x = cvtpk_bf16(xlo[j].x, xlo[j].y);
      wv4.y = cvtpk_bf16(xlo[j].z, xlo[j].w);
      wv4.z = cvtpk_bf16(xhi[j].x, xhi[j].y);
      wv4.w = cvtpk_bf16(xhi[j].z, xhi[j].w);
      *(uint4*)&sX[bi][dOff[j]] = wv4;
    }
  };
  auto stageW = [&](int k0, int bi) {
#pragma unroll
    for (int j = 0; j < 4; ++j) cp16(Ws + wSrc[j] + k0, &sW[bi][dOff[j]]);
  };

  // prologue: tile 0
  loadX(0);
  stageW(0, 0);
  writeX(0);
  __syncthreads();   // drains vmcnt (cp16) + lgkm (ds_writes): tile 0 resident
  int buf = 0;
  for (int k0 = 0; k0 < KDIM; k0 += 64) {
    const bool more = (k0 + 64 < KDIM);
    if (more) { loadX(k0 + 64); stageW(k0 + 64, buf ^ 1); }
    __builtin_amdgcn_s_setprio(1);
    const u16* sAf = vtr ? &sX[buf][0] : &sW[buf][0];
    const u16* sBf = vtr ? &sW[buf][0] : &sX[buf][0];
#pragma unroll
    for (int h = 0; h < 2; ++h) {
      bf16x8 af[4], bf[4];
#pragma unroll
      for (int i = 0; i < 4; ++i) {
        const int ar = arow + i * 16, br = brow + i * 16;
        af[i] = *(const bf16x8*)&sAf[ar * 64 + (((h * 4 + quad) ^ (ar & 7)) << 3)];
        bf[i] = *(const bf16x8*)&sBf[br * 64 + (((h * 4 + quad) ^ (br & 7)) << 3)];
      }
#pragma unroll
      for (int mi = 0; mi < 4; ++mi)
#pragma unroll
        for (int ni = 0; ni < 4; ++ni)
          acc[mi][ni] = mfma16(af[mi], bf[ni], acc[mi][ni]);
    }
    __builtin_amdgcn_s_setprio(0);
    if (more) writeX(buf ^ 1);   // waits the X loads (post-MFMA: latency hidden)
    __syncthreads();             // cp16 drained + writes visible; protects buf
    buf ^= 1;
  }

  if (!vtr) {
    // Q/K epilogue: rows = feats, lanes = tokens. RoPE in-register.
    u16* C = tsel == 0 ? Qp : Kp;
#pragma unroll
    for (int mi = 0; mi < 4; ++mi) {
      const int fm = fBase + wr * 64 + mi * 16 + quad * 4;   // 4-aligned feat
      const float4 b4 = *(const float4*)&bias[fm];
      const int d0 = fm & 63;
#pragma unroll
      for (int ni = 0; ni < 4; ++ni) {
        const int t = tBase + wc * 64 + ni * 16 + l16;
        const int srow = t & (SS - 1);
        const float* cs = &csT[(size_t)((srow << 6) + d0) * 2];
        const float4 cs01 = *(const float4*)cs;        // c0 s0 c1 s1
        const float4 cs23 = *(const float4*)(cs + 4);  // c2 s2 c3 s3
        const float v0 = acc[mi][ni][0] + b4.x;
        const float v1 = acc[mi][ni][1] + b4.y;
        const float v2 = acc[mi][ni][2] + b4.z;
        const float v3 = acc[mi][ni][3] + b4.w;
        const float o0 = v0 * cs01.x - v1 * cs01.y;
        const float o1 = v1 * cs01.z + v0 * cs01.w;
        const float o2 = v2 * cs23.x - v3 * cs23.y;
        const float o3 = v3 * cs23.z + v2 * cs23.w;
        uint2 pk;
        pk.x = cvtpk_bf16(o0, o1);
        pk.y = cvtpk_bf16(o2, o3);
        *(uint2*)&C[(size_t)t * NDIM + fm] = pk;
      }
    }
  } else {
    // V epilogue: rows = tokens (4-aligned -> 4 consecutive sp), lanes = feats.
#pragma unroll
    for (int ni = 0; ni < 4; ++ni) {
      const int f = fBase + wc * 64 + ni * 16 + l16;
      const int h = f >> 6, d = f & 63;
      const float bb = bias[f];
#pragma unroll
      for (int mi = 0; mi < 4; ++mi) {
        const int t0 = tBase + wr * 64 + mi * 16 + quad * 4;
        const int b = t0 >> 11, s0 = t0 & (SS - 1);
        const int sp0 = (s0 & ~31) | (((s0 >> 2) & 3) << 3) | (((s0 >> 4) & 1) << 2);
        uint2 pk;
        pk.x = cvtpk_bf16(acc[mi][ni][0] + bb, acc[mi][ni][1] + bb);
        pk.y = cvtpk_bf16(acc[mi][ni][2] + bb, acc[mi][ni][3] + bb);
        *(uint2*)&Vtg[((size_t)((b * 16 + h) * 64 + d)) * SS + sp0] = pk;
      }
    }
  }
}

// ---------------- flash attention: split-K wave groups (R5, proven) ---------
// 512 thr = 8 waves = 2 key-groups x 4 waves. Both groups cover the same 128
// q-rows (32/wave, 2 frags -> every ds_read feeds 2 MFMAs); group g handles
// 64-key chunk of each step. Fixed-max softmax => partial (O,l) combine by
// plain addition in LDS at the end. 72KB LDS, 2 blocks/CU -> 16 waves/CU.
__global__ __launch_bounds__(512, 4) void attn_kernel(
    const u16* __restrict__ Qp, const u16* __restrict__ Kp, const u16* __restrict__ Vtg,
    const float* __restrict__ mfl, u16* __restrict__ Oh) {
  // layout (u16 idx): grp g: K[bi] at g*16384 + bi*4096, V[bi] at g*16384+8192+bi*4096
  // mask floats at u16 32768 (8KB). Epilogue overlays: sO f32 over [0..], l0 over mask.
  __shared__ alignas(16) u16 sm[36864];   // 72 KB
  // grid = (16, 32), 512 blocks = 8 XCDs x 64.
  const int flat = blockIdx.y * 16 + blockIdx.x;
  const int swz = (flat & 7) * 64 + (flat >> 3);
  const int bqx = swz & 15, bh = swz >> 4;   // bh in [xcd*4, xcd*4+4)

  const int tid = threadIdx.x, lane = tid & 63, w = tid >> 6;
  const int quad = lane >> 4, l16 = lane & 15;
  const int b = bh >> 4, h = bh & 15;
  const int q0 = bqx * 128 + (w & 3) * 32;   // wave owns 32 q rows
  const int grp = w >> 2, wl = w & 3;
  const u16* Qb = Qp + (size_t)b * SS * EE + h * DD;
  const u16* Kb = Kp + (size_t)b * SS * EE + h * DD;
  const u16* Vb = Vtg + (size_t)bh * DD * SS;
  constexpr float C1 = 0.18033688011112042f;   // (1/sqrt(64)) * log2(e)
  float* smask = (float*)&sm[32768];

  bf16x8 qf[2][2];   // [q-frag][ks]
#pragma unroll
  for (int qi = 0; qi < 2; ++qi)
#pragma unroll
    for (int ks = 0; ks < 2; ++ks)
      qf[qi][ks] = *(const bf16x8*)(Qb + (size_t)(q0 + qi * 16 + l16) * EE + ks * 32 + quad * 8);

  f32x4 oacc[2][4];
#pragma unroll
  for (int qi = 0; qi < 2; ++qi)
#pragma unroll
    for (int nd = 0; nd < 4; ++nd)
#pragma unroll
      for (int e = 0; e < 4; ++e) oacc[qi][nd][e] = 0.f;
  f32x2 sum2[2];
  sum2[0] = {0.f, 0.f}; sum2[1] = {0.f, 0.f};

  const int gtid = tid & 255;   // thread within group

  // -------- stage this group's 64-key chunk of step w_ into buffer bi ------
  auto stage = [&](int w_, int bi) {
    const int key0 = w_ * 128 + grp * 64;
    u16* dK = &sm[grp * 16384 + bi * 4096];
    u16* dV = &sm[grp * 16384 + 8192 + bi * 4096];
#pragma unroll
    for (int i = 0; i < 2; ++i) {
      const int c = i * 256 + gtid;          // 512 chunks of 16B (8KB)
      const int key = c >> 3, sl = c & 7;
      cp16(Kb + (size_t)(key0 + key) * EE + ((sl ^ (key & 7)) * 8), &dK[c * 8]);
    }
#pragma unroll
    for (int i = 0; i < 2; ++i) {
      const int c = i * 256 + gtid;
      const int d = c >> 3, sl = c & 7;
      cp16(Vb + (size_t)d * SS + key0 + ((sl ^ (d & 7)) * 8), &dV[c * 8]);
    }
  };

  // -------- compute this group's 64-key chunk of step w_ from buffer bi ----
  auto compute = [&](int w_, int bi) {
    const int key0 = w_ * 128 + grp * 64;
    const u16* sK_ = &sm[grp * 16384 + bi * 4096];
    const u16* sV_ = &sm[grp * 16384 + 8192 + bi * 4096];
    // S^T = K * Q^T : D[m=key][n=q], per q-frag
    f32x4 sacc[2][4];
#pragma unroll
    for (int qi = 0; qi < 2; ++qi)
#pragma unroll
      for (int ni = 0; ni < 4; ++ni)
#pragma unroll
        for (int e = 0; e < 4; ++e) sacc[qi][ni][e] = 0.f;
    __builtin_amdgcn_s_setprio(1);
#pragma unroll
    for (int ks = 0; ks < 2; ++ks)
#pragma unroll
      for (int ni = 0; ni < 4; ++ni) {
        const int row = ni * 16 + l16;  // key
        const bf16x8 kf = *(const bf16x8*)&sK_[row * 64 + (((ks * 4 + quad) ^ (l16 & 7)) << 3)];
#pragma unroll
        for (int qi = 0; qi < 2; ++qi)
          sacc[qi][ni] = mfma16(kf, qf[qi][ks], sacc[qi][ni]);
      }
    __builtin_amdgcn_s_setprio(0);

    // hoisted mask loads: same values for both q-frags (was 2x the LDS reads)
    f32x2 mh01[4], mh23[4];
#pragma unroll
    for (int ni = 0; ni < 4; ++ni) {
      const int kb4 = key0 + ni * 16 + quad * 4;
      mh01[ni] = *(const f32x2*)&smask[kb4];
      mh23[ni] = *(const f32x2*)&smask[kb4 + 2];
    }

    // single-pass softmax: p = exp2(s*C1 + mval); raw v_exp_f32.
    uint32_t pw32[2][2][4];
#pragma unroll
    for (int qi = 0; qi < 2; ++qi)
#pragma unroll
      for (int ni = 0; ni < 4; ++ni) {
        f32x2 t01, t23;
        t01.x = sacc[qi][ni][0]; t01.y = sacc[qi][ni][1];
        t23.x = sacc[qi][ni][2]; t23.y = sacc[qi][ni][3];
        t01 = t01 * C1 + mh01[ni];
        t23 = t23 * C1 + mh23[ni];
        f32x2 p01, p23;
        p01.x = __builtin_amdgcn_exp2f(t01.x); p01.y = __builtin_amdgcn_exp2f(t01.y);
        p23.x = __builtin_amdgcn_exp2f(t23.x); p23.y = __builtin_amdgcn_exp2f(t23.y);
        sum2[qi] += p01;
        sum2[qi] += p23;
        const int k2 = ni >> 1, j2 = (ni & 1) * 2;
        pw32[qi][k2][j2]     = cvtpk_bf16(p01.x, p01.y);
        pw32[qi][k2][j2 + 1] = cvtpk_bf16(p23.x, p23.y);
      }

    // O += P @ V  (K=32, pi-permuted key order on both operands)
    __builtin_amdgcn_s_setprio(1);
#pragma unroll
    for (int k2 = 0; k2 < 2; ++k2) {
      union { uint32_t u[4]; bf16x8 v; } pf[2];
#pragma unroll
      for (int qi = 0; qi < 2; ++qi)
#pragma unroll
        for (int j = 0; j < 4; ++j) pf[qi].u[j] = pw32[qi][k2][j];
#pragma unroll
      for (int nd = 0; nd < 4; ++nd) {
        const int row = nd * 16 + l16;  // d
        const bf16x8 vf = *(const bf16x8*)&sV_[row * 64 + (((k2 * 4 + quad) ^ (l16 & 7)) << 3)];
#pragma unroll
        for (int qi = 0; qi < 2; ++qi)
          oacc[qi][nd] = mfma16(pf[qi].v, vf, oacc[qi][nd]);
      }
    }
    __builtin_amdgcn_s_setprio(0);
  };

  // prologue: stage step 0 + full mask row, then drain.
  stage(0, 0);
  cp16(mfl + (size_t)b * SS + tid * 4, &sm[32768 + tid * 8]);   // 512 x 16B = 8KB
  __syncthreads();

  for (int w_ = 0; w_ < 16; ++w_) {
    if (w_ + 1 < 16) stage(w_ + 1, (w_ + 1) & 1);
    compute(w_, w_ & 1);
    __syncthreads();   // drains vmcnt: next chunk ready; protects parity buffer
  }

  // group-partial l per q row (sum over this group's keys)
  float lg[2];
#pragma unroll
  for (int qi = 0; qi < 2; ++qi) {
    float s = sum2[qi].x + sum2[qi].y;
    s += __shfl_xor(s, 16, 64);
    s += __shfl_xor(s, 32, 64);
    lg[qi] = s;   // uniform across quads; indexed by q=l16 within frag
  }

  // combine partials in LDS (K/V buffers + mask are dead now)
  float* sO = (float*)&sm[0];          // [128][stride 65] f32
  float* l0 = smask;                   // 128 floats
  if (grp == 0) {
#pragma unroll
    for (int qi = 0; qi < 2; ++qi)
#pragma unroll
      for (int nd = 0; nd < 4; ++nd)
#pragma unroll
        for (int e = 0; e < 4; ++e) {
          const int q = wl * 32 + qi * 16 + quad * 4 + e;
          sO[q * 65 + nd * 16 + l16] = oacc[qi][nd][e];
        }
    if (quad == 0) {
      l0[wl * 32 + l16] = lg[0];
      l0[wl * 32 + 16 + l16] = lg[1];
    }
  }
  __syncthreads();
  if (grp == 1) {
    float linv[2];
#pragma unroll
    for (int qi = 0; qi < 2; ++qi) {
      const float lt = l0[wl * 32 + qi * 16 + l16] + lg[qi];
      linv[qi] = lt > 0.f ? 1.0f / lt : 0.f;
    }
#pragma unroll
    for (int qi = 0; qi < 2; ++qi)
#pragma unroll
      for (int r = 0; r < 4; ++r) {
        const float li = __shfl(linv[qi], quad * 4 + r, 16);
        const int q = wl * 32 + qi * 16 + quad * 4 + r;
        const size_t row = (size_t)(b * SS + bqx * 128 + q) * EE + h * DD;
#pragma unroll
        for (int nd = 0; nd < 4; ++nd) {
          const int d = nd * 16 + l16;
          Oh[row + d] = f2bf((sO[q * 65 + d] + oacc[qi][nd][r]) * li);
        }
      }
  }
}

// ---------------- output projection: prefetch dbuf bf16, 128x64, BK=64 ------
// (R5 version, proven)
__global__ __launch_bounds__(256) void gemm_out(
    const u16* __restrict__ Ab, const u16* __restrict__ Bb,
    const float* __restrict__ bias, float* __restrict__ Cout) {
  __shared__ alignas(16) u16 sA[2][128 * 64];
  __shared__ alignas(16) u16 sB[2][64 * 64];
  // grid = (16, 32), 512 blocks = 8 XCDs x 64.
  const int flat = blockIdx.y * 16 + blockIdx.x;
  const int swz = (flat & 7) * 64 + (flat >> 3);
  const int bx = swz & 15, by = swz >> 4;

  const int rowBase = by * 128;
  const int colBase = bx * 64;
  const int tid = threadIdx.x;
  const int lane = tid & 63, w = tid >> 6;
  const int quad = lane >> 4, l16 = lane & 15;
  const int wr = w >> 1, wc = w & 1;

  size_t aSrc[4]; int aOff[4];
  size_t bSrc[2]; int bOff[2];
#pragma unroll
  for (int j = 0; j < 4; ++j) {
    const int c = tid + j * 256;
    const int row = c >> 3, sl = c & 7;
    aSrc[j] = (size_t)(rowBase + row) * KDIM + ((sl ^ (row & 7)) * 8);
    aOff[j] = c * 8;
  }
#pragma unroll
  for (int j = 0; j < 2; ++j) {
    const int c = tid + j * 256;
    const int row = c >> 3, sl = c & 7;
    bSrc[j] = (size_t)(colBase + row) * KDIM + ((sl ^ (row & 7)) * 8);
    bOff[j] = c * 8;
  }

  f32x4 acc[4][2];
#pragma unroll
  for (int mi = 0; mi < 4; ++mi)
#pragma unroll
    for (int ni = 0; ni < 2; ++ni)
#pragma unroll
      for (int e = 0; e < 4; ++e) acc[mi][ni][e] = 0.f;

  const int arow = wr * 64 + l16, brow = wc * 32 + l16;

  auto stage = [&](int k0, int bi) {
#pragma unroll
    for (int j = 0; j < 4; ++j) cp16(Ab + aSrc[j] + k0, &sA[bi][aOff[j]]);
#pragma unroll
    for (int j = 0; j < 2; ++j) cp16(Bb + bSrc[j] + k0, &sB[bi][bOff[j]]);
  };

  stage(0, 0);
  __syncthreads();
  int buf = 0;
  for (int k0 = 0; k0 < KDIM; k0 += 64) {
    if (k0 + 64 < KDIM) stage(k0 + 64, buf ^ 1);
    __builtin_amdgcn_s_setprio(1);
#pragma unroll
    for (int h = 0; h < 2; ++h) {
      bf16x8 af[4], bf[2];
#pragma unroll
      for (int i = 0; i < 4; ++i) {
        const int ar = arow + i * 16;
        af[i] = *(const bf16x8*)&sA[buf][ar * 64 + (((h * 4 + quad) ^ (ar & 7)) << 3)];
      }
#pragma unroll
      for (int i = 0; i < 2; ++i) {
        const int br = brow + i * 16;
        bf[i] = *(const bf16x8*)&sB[buf][br * 64 + (((h * 4 + quad) ^ (br & 7)) << 3)];
      }
#pragma unroll
      for (int mi = 0; mi < 4; ++mi)
#pragma unroll
        for (int ni = 0; ni < 2; ++ni)
          acc[mi][ni] = mfma16(af[mi], bf[ni], acc[mi][ni]);
    }
    __builtin_amdgcn_s_setprio(0);
    __syncthreads();
    buf ^= 1;
  }

#pragma unroll
  for (int mi = 0; mi < 4; ++mi) {
    const int rb = rowBase + wr * 64 + mi * 16 + quad * 4;
#pragma unroll
    for (int ni = 0; ni < 2; ++ni) {
      const int col = colBase + wc * 32 + ni * 16 + l16;
      const float bb = bias[col];
#pragma unroll
      for (int r = 0; r < 4; ++r)
        Cout[(size_t)(rb + r) * NDIM + col] = acc[mi][ni][r] + bb;
    }
  }
}

// ---------------- host launch ----------------
extern "C" void kernel_launch(void* const* d_in, const int* in_sizes, int n_in,
                              void* d_out, int out_size, void* d_ws, size_t ws_size,
                              hipStream_t stream) {
  const float* q    = (const float*)d_in[0];
  const float* k    = (const float*)d_in[1];
  const float* v    = (const float*)d_in[2];
  const int*   mask = (const int*)d_in[3];
  const float* Wq = (const float*)d_in[4];
  const float* bq = (const float*)d_in[5];
  const float* Wk = (const float*)d_in[6];
  const float* bk = (const float*)d_in[7];
  const float* Wv = (const float*)d_in[8];
  const float* bv = (const float*)d_in[9];
  const float* Wo = (const float*)d_in[10];
  const float* bo = (const float*)d_in[11];
  float* out = (float*)d_out;
  char* ws = (char*)d_ws;
  constexpr size_t MB = 1024 * 1024;
  u16* wqb = (u16*)(ws + 24 * MB);
  u16* wkb = (u16*)(ws + 26 * MB);
  u16* wvb = (u16*)(ws + 28 * MB);
  u16* wob = (u16*)(ws + 30 * MB);
  u16* Qp  = (u16*)(ws + 32 * MB);
  u16* Kp  = (u16*)(ws + 40 * MB);
  u16* Vtg = (u16*)(ws + 48 * MB);   // V^T head-major, pi-permuted keys
  u16* oh  = (u16*)(ws + 56 * MB);
  float* csT = (float*)(ws + 64 * MB);   // [s][d] {cos,sin}, 1 MB
  // mask floats live in d_out: written by prep_w, read by attn_kernel,
  // then gemm_out overwrites the whole output buffer afterwards. 16KB << 16MB.
  float* mfl = out;

  prep_w<<<4096, 256, 0, stream>>>(Wq, Wk, Wv, Wo, mask,
                                   wqb, wkb, wvb, wob, csT, mfl);
  gemm_qkv<<<dim3(8, 96), 256, 0, stream>>>(q, k, v, wqb, wkb, wvb,
                                            bq, bk, bv, Qp, Kp, Vtg, csT);
  attn_kernel<<<dim3(16, 32), 512, 0, stream>>>(Qp, Kp, Vtg, mfl, oh);
  gemm_out<<<dim3(16, 32), 256, 0, stream>>>(oh, wob, bo, out);
}

// Round 11
// 218.958 us; speedup vs baseline: 1.1067x; 1.1067x over previous
//
#include <hip/hip_runtime.h>
#include <stdint.h>

typedef unsigned short u16;
typedef __bf16 bf16x8 __attribute__((ext_vector_type(8)));
typedef float f32x4 __attribute__((ext_vector_type(4)));
typedef float f32x2 __attribute__((ext_vector_type(2)));
typedef u16 u16x4v __attribute__((ext_vector_type(4)));

#define DI __device__ __forceinline__

constexpr int BB = 2, SS = 2048, EE = 1024, HH = 16, DD = 64;
constexpr int MROWS = BB * SS;   // 4096 tokens
constexpr int KDIM = 1024, NDIM = 1024;

constexpr float FM = 12.0f;      // fixed max offset (log2 domain)
constexpr float MNEG = -30000.f;

DI u16 f2bf(float f) {  // RNE float->bf16 (finite inputs)
  uint32_t u = __float_as_uint(f);
  return (u16)((u + 0x7FFFu + ((u >> 16) & 1u)) >> 16);
}
DI float bf2f(u16 h) { return __uint_as_float(((uint32_t)h) << 16); }

DI uint32_t cvtpk_bf16(float a, float b) {  // low=bf16(a), high=bf16(b), RNE
  uint32_t r;
  asm("v_cvt_pk_bf16_f32 %0, %1, %2" : "=v"(r) : "v"(a), "v"(b));
  return r;
}

DI void cp16(const void* g, void* lds) {
  __builtin_amdgcn_global_load_lds((const __attribute__((address_space(1))) void*)g,
                                   (__attribute__((address_space(3))) void*)lds, 16, 0, 0);
}

DI f32x4 mfma16(bf16x8 a, bf16x8 b, f32x4 c) {
  return __builtin_amdgcn_mfma_f32_16x16x32_bf16(a, b, c, 0, 0, 0);
}

// ---------------- prep: fp32 -> bf16 casts + RoPE table + mask floats -------
// rope/mask work rides along in the first 512 blocks (hidden under the
// memory-bound cast) -- saves a separate dispatch.
__global__ __launch_bounds__(256) void prep_cast(
    const float* __restrict__ q, const float* __restrict__ k, const float* __restrict__ v,
    const float* __restrict__ wq, const float* __restrict__ wk, const float* __restrict__ wv,
    const float* __restrict__ wo, const int* __restrict__ mask,
    u16* __restrict__ qb, u16* __restrict__ kb, u16* __restrict__ vb,
    u16* __restrict__ wqb, u16* __restrict__ wkb, u16* __restrict__ wvb,
    u16* __restrict__ wob, float* __restrict__ csT, float* __restrict__ mfl) {
  constexpr size_t SZI = (size_t)MROWS * EE;  // 4M
  constexpr size_t SZW = (size_t)EE * EE;     // 1M
  const int t = blockIdx.x * 256 + threadIdx.x;
  if (t < SS * 64) {   // RoPE table: csT[s][d] = {cos, sin}
    const int s = t >> 6, d = t & 63, j = d & 31;
    const float ang = (float)s * exp2f(-(float)j * 0.4152410118f);
    float2 cs; cs.x = cosf(ang); cs.y = sinf(ang);
    ((float2*)csT)[t] = cs;
    if (t < BB * SS) mfl[t] = mask[t] ? -FM : MNEG;
  }
  const size_t g = ((size_t)blockIdx.x * 256 + threadIdx.x) * 4;
  const float* src; u16* dst; size_t o;
  if (g < SZI)          { src = q; dst = qb; o = g; }
  else if (g < 2 * SZI) { src = k; dst = kb; o = g - SZI; }
  else if (g < 3 * SZI) { src = v; dst = vb; o = g - 2 * SZI; }
  else {
    size_t t2 = g - 3 * SZI;
    int wi = (int)(t2 / SZW);
    o = t2 - (size_t)(wi < 4 ? wi : 3) * SZW;   // wi==4 tail duplicates wo (benign)
    src = wi == 0 ? wq : wi == 1 ? wk : wi == 2 ? wv : wo;
    dst = wi == 0 ? wqb : wi == 1 ? wkb : wi == 2 ? wvb : wob;
  }
  const float4 f = *(const float4*)(src + o);
  u16x4v hv;
  hv[0] = f2bf(f.x); hv[1] = f2bf(f.y); hv[2] = f2bf(f.z); hv[3] = f2bf(f.w);
  *(u16x4v*)(dst + o) = hv;
}

// ---------------- QKV projection GEMM, BK=64, prefetch double-buffer --------
// Q/K: A = W (m=feat), B = X (n=token), RoPE in-register.
// V  : A = X (m=token), B = Wv (n=feat); Vtg keys pi-permuted in 32-groups.
__global__ __launch_bounds__(256) void gemm_qkv(
    const u16* __restrict__ qb, const u16* __restrict__ kb, const u16* __restrict__ vb,
    const u16* __restrict__ wqb, const u16* __restrict__ wkb, const u16* __restrict__ wvb,
    const float* __restrict__ bq, const float* __restrict__ bk, const float* __restrict__ bv,
    u16* __restrict__ Qp, u16* __restrict__ Kp, u16* __restrict__ Vtg,
    const float* __restrict__ csT) {
  __shared__ alignas(16) u16 sA[2][128 * 64];
  __shared__ alignas(16) u16 sB[2][128 * 64];
  // grid = (8, 96), 768 blocks = 8 XCDs x 96. hw id % 8 = XCD.
  const int flat = blockIdx.y * 8 + blockIdx.x;
  const int swz = (flat & 7) * 96 + (flat >> 3);
  const int bx = swz & 7, by = swz >> 3;   // by in [xcd*12, xcd*12+12)

  const int tsel = by >> 5;  // 0=Q 1=K 2=V
  const bool vtr = (tsel == 2);
  const u16* A    = tsel == 0 ? wqb : tsel == 1 ? wkb : vb;
  const u16* Bm   = tsel == 0 ? qb  : tsel == 1 ? kb  : wvb;
  const float* bias = tsel == 0 ? bq : tsel == 1 ? bk : bv;

  const int fBase = bx * 128;          // feature block (8)
  const int tBase = (by & 31) * 128;   // token block (32)
  const int aBase = vtr ? tBase : fBase;
  const int bBase = vtr ? fBase : tBase;
  const int tid = threadIdx.x;
  const int lane = tid & 63, w = tid >> 6;
  const int quad = lane >> 4, l16 = lane & 15;
  const int wr = w >> 1, wc = w & 1;

  size_t aSrc[4], bSrc[4];
  int dOff[4];
#pragma unroll
  for (int j = 0; j < 4; ++j) {
    const int c = tid + j * 256;
    const int row = c >> 3, sl = c & 7;
    const size_t off = (size_t)row * KDIM + ((sl ^ (row & 7)) * 8);
    aSrc[j] = (size_t)aBase * KDIM + off;
    bSrc[j] = (size_t)bBase * KDIM + off;
    dOff[j] = c * 8;
  }

  f32x4 acc[4][4];
#pragma unroll
  for (int mi = 0; mi < 4; ++mi)
#pragma unroll
    for (int ni = 0; ni < 4; ++ni)
#pragma unroll
      for (int e = 0; e < 4; ++e) acc[mi][ni][e] = 0.f;

  const int arow = wr * 64 + l16, brow = wc * 64 + l16;

  auto stage = [&](int k0, int bi) {
#pragma unroll
    for (int j = 0; j < 4; ++j) {
      cp16(A + aSrc[j] + k0, &sA[bi][dOff[j]]);
      cp16(Bm + bSrc[j] + k0, &sB[bi][dOff[j]]);
    }
  };

  stage(0, 0);
  __syncthreads();   // drains vmcnt(0): tile 0 resident
  int buf = 0;
  for (int k0 = 0; k0 < KDIM; k0 += 64) {
    if (k0 + 64 < KDIM) stage(k0 + 64, buf ^ 1);
    __builtin_amdgcn_s_setprio(1);
#pragma unroll
    for (int h = 0; h < 2; ++h) {
      bf16x8 af[4], bf[4];
#pragma unroll
      for (int i = 0; i < 4; ++i) {
        const int ar = arow + i * 16, br = brow + i * 16;
        af[i] = *(const bf16x8*)&sA[buf][ar * 64 + (((h * 4 + quad) ^ (ar & 7)) << 3)];
        bf[i] = *(const bf16x8*)&sB[buf][br * 64 + (((h * 4 + quad) ^ (br & 7)) << 3)];
      }
#pragma unroll
      for (int mi = 0; mi < 4; ++mi)
#pragma unroll
        for (int ni = 0; ni < 4; ++ni)
          acc[mi][ni] = mfma16(af[mi], bf[ni], acc[mi][ni]);
    }
    __builtin_amdgcn_s_setprio(0);
    __syncthreads();   // drains vmcnt: next tile ready; protects buf for restage
    buf ^= 1;
  }

  if (!vtr) {
    // Q/K epilogue: rows = feats, lanes = tokens. RoPE in-register.
    u16* C = tsel == 0 ? Qp : Kp;
#pragma unroll
    for (int mi = 0; mi < 4; ++mi) {
      const int fm = fBase + wr * 64 + mi * 16 + quad * 4;   // 4-aligned feat
      const float4 b4 = *(const float4*)&bias[fm];
      const int d0 = fm & 63;
#pragma unroll
      for (int ni = 0; ni < 4; ++ni) {
        const int t = tBase + wc * 64 + ni * 16 + l16;
        const int srow = t & (SS - 1);
        const float* cs = &csT[(size_t)((srow << 6) + d0) * 2];
        const float4 cs01 = *(const float4*)cs;        // c0 s0 c1 s1
        const float4 cs23 = *(const float4*)(cs + 4);  // c2 s2 c3 s3
        const float v0 = acc[mi][ni][0] + b4.x;
        const float v1 = acc[mi][ni][1] + b4.y;
        const float v2 = acc[mi][ni][2] + b4.z;
        const float v3 = acc[mi][ni][3] + b4.w;
        const float o0 = v0 * cs01.x - v1 * cs01.y;
        const float o1 = v1 * cs01.z + v0 * cs01.w;
        const float o2 = v2 * cs23.x - v3 * cs23.y;
        const float o3 = v3 * cs23.z + v2 * cs23.w;
        uint2 pk;
        pk.x = cvtpk_bf16(o0, o1);
        pk.y = cvtpk_bf16(o2, o3);
        *(uint2*)&C[(size_t)t * NDIM + fm] = pk;
      }
    }
  } else {
    // V epilogue: rows = tokens (4-aligned -> 4 consecutive sp), lanes = feats.
#pragma unroll
    for (int ni = 0; ni < 4; ++ni) {
      const int f = fBase + wc * 64 + ni * 16 + l16;
      const int h = f >> 6, d = f & 63;
      const float bb = bias[f];
#pragma unroll
      for (int mi = 0; mi < 4; ++mi) {
        const int t0 = tBase + wr * 64 + mi * 16 + quad * 4;
        const int b = t0 >> 11, s0 = t0 & (SS - 1);
        const int sp0 = (s0 & ~31) | (((s0 >> 2) & 3) << 3) | (((s0 >> 4) & 1) << 2);
        uint2 pk;
        pk.x = cvtpk_bf16(acc[mi][ni][0] + bb, acc[mi][ni][1] + bb);
        pk.y = cvtpk_bf16(acc[mi][ni][2] + bb, acc[mi][ni][3] + bb);
        *(uint2*)&Vtg[((size_t)((b * 16 + h) * 64 + d)) * SS + sp0] = pk;
      }
    }
  }
}

// ---------------- flash attention: split-K wave groups (R5, proven) ---------
// 512 thr = 8 waves = 2 key-groups x 4 waves. Both groups cover the same 128
// q-rows (32/wave, 2 frags -> every ds_read feeds 2 MFMAs); group g handles
// 64-key chunk of each step. Fixed-max softmax => partial (O,l) combine by
// plain addition in LDS at the end. 72KB LDS, 2 blocks/CU -> 16 waves/CU.
__global__ __launch_bounds__(512, 4) void attn_kernel(
    const u16* __restrict__ Qp, const u16* __restrict__ Kp, const u16* __restrict__ Vtg,
    const float* __restrict__ mfl, u16* __restrict__ Oh) {
  // layout (u16 idx): grp g: K[bi] at g*16384 + bi*4096, V[bi] at g*16384+8192+bi*4096
  // mask floats at u16 32768 (8KB). Epilogue overlays: sO f32 over [0..], l0 over mask.
  __shared__ alignas(16) u16 sm[36864];   // 72 KB
  // grid = (16, 32), 512 blocks = 8 XCDs x 64.
  const int flat = blockIdx.y * 16 + blockIdx.x;
  const int swz = (flat & 7) * 64 + (flat >> 3);
  const int bqx = swz & 15, bh = swz >> 4;   // bh in [xcd*4, xcd*4+4)

  const int tid = threadIdx.x, lane = tid & 63, w = tid >> 6;
  const int quad = lane >> 4, l16 = lane & 15;
  const int b = bh >> 4, h = bh & 15;
  const int q0 = bqx * 128 + (w & 3) * 32;   // wave owns 32 q rows
  const int grp = w >> 2, wl = w & 3;
  const u16* Qb = Qp + (size_t)b * SS * EE + h * DD;
  const u16* Kb = Kp + (size_t)b * SS * EE + h * DD;
  const u16* Vb = Vtg + (size_t)bh * DD * SS;
  constexpr float C1 = 0.18033688011112042f;   // (1/sqrt(64)) * log2(e)
  float* smask = (float*)&sm[32768];

  bf16x8 qf[2][2];   // [q-frag][ks]
#pragma unroll
  for (int qi = 0; qi < 2; ++qi)
#pragma unroll
    for (int ks = 0; ks < 2; ++ks)
      qf[qi][ks] = *(const bf16x8*)(Qb + (size_t)(q0 + qi * 16 + l16) * EE + ks * 32 + quad * 8);

  f32x4 oacc[2][4];
#pragma unroll
  for (int qi = 0; qi < 2; ++qi)
#pragma unroll
    for (int nd = 0; nd < 4; ++nd)
#pragma unroll
      for (int e = 0; e < 4; ++e) oacc[qi][nd][e] = 0.f;
  f32x2 sum2[2];
  sum2[0] = {0.f, 0.f}; sum2[1] = {0.f, 0.f};

  const int gtid = tid & 255;   // thread within group

  // -------- stage this group's 64-key chunk of step w_ into buffer bi ------
  auto stage = [&](int w_, int bi) {
    const int key0 = w_ * 128 + grp * 64;
    u16* dK = &sm[grp * 16384 + bi * 4096];
    u16* dV = &sm[grp * 16384 + 8192 + bi * 4096];
#pragma unroll
    for (int i = 0; i < 2; ++i) {
      const int c = i * 256 + gtid;          // 512 chunks of 16B (8KB)
      const int key = c >> 3, sl = c & 7;
      cp16(Kb + (size_t)(key0 + key) * EE + ((sl ^ (key & 7)) * 8), &dK[c * 8]);
    }
#pragma unroll
    for (int i = 0; i < 2; ++i) {
      const int c = i * 256 + gtid;
      const int d = c >> 3, sl = c & 7;
      cp16(Vb + (size_t)d * SS + key0 + ((sl ^ (d & 7)) * 8), &dV[c * 8]);
    }
  };

  // -------- compute this group's 64-key chunk of step w_ from buffer bi ----
  auto compute = [&](int w_, int bi) {
    const int key0 = w_ * 128 + grp * 64;
    const u16* sK_ = &sm[grp * 16384 + bi * 4096];
    const u16* sV_ = &sm[grp * 16384 + 8192 + bi * 4096];
    // S^T = K * Q^T : D[m=key][n=q], per q-frag
    f32x4 sacc[2][4];
#pragma unroll
    for (int qi = 0; qi < 2; ++qi)
#pragma unroll
      for (int ni = 0; ni < 4; ++ni)
#pragma unroll
        for (int e = 0; e < 4; ++e) sacc[qi][ni][e] = 0.f;
    __builtin_amdgcn_s_setprio(1);
#pragma unroll
    for (int ks = 0; ks < 2; ++ks)
#pragma unroll
      for (int ni = 0; ni < 4; ++ni) {
        const int row = ni * 16 + l16;  // key
        const bf16x8 kf = *(const bf16x8*)&sK_[row * 64 + (((ks * 4 + quad) ^ (l16 & 7)) << 3)];
#pragma unroll
        for (int qi = 0; qi < 2; ++qi)
          sacc[qi][ni] = mfma16(kf, qf[qi][ks], sacc[qi][ni]);
      }
    __builtin_amdgcn_s_setprio(0);

    // hoisted mask loads: same values for both q-frags (was 2x the LDS reads)
    f32x2 mh01[4], mh23[4];
#pragma unroll
    for (int ni = 0; ni < 4; ++ni) {
      const int kb4 = key0 + ni * 16 + quad * 4;
      mh01[ni] = *(const f32x2*)&smask[kb4];
      mh23[ni] = *(const f32x2*)&smask[kb4 + 2];
    }

    // single-pass softmax: p = exp2(s*C1 + mval); raw v_exp_f32.
    uint32_t pw32[2][2][4];
#pragma unroll
    for (int qi = 0; qi < 2; ++qi)
#pragma unroll
      for (int ni = 0; ni < 4; ++ni) {
        f32x2 t01, t23;
        t01.x = sacc[qi][ni][0]; t01.y = sacc[qi][ni][1];
        t23.x = sacc[qi][ni][2]; t23.y = sacc[qi][ni][3];
        t01 = t01 * C1 + mh01[ni];
        t23 = t23 * C1 + mh23[ni];
        f32x2 p01, p23;
        p01.x = __builtin_amdgcn_exp2f(t01.x); p01.y = __builtin_amdgcn_exp2f(t01.y);
        p23.x = __builtin_amdgcn_exp2f(t23.x); p23.y = __builtin_amdgcn_exp2f(t23.y);
        sum2[qi] += p01;
        sum2[qi] += p23;
        const int k2 = ni >> 1, j2 = (ni & 1) * 2;
        pw32[qi][k2][j2]     = cvtpk_bf16(p01.x, p01.y);
        pw32[qi][k2][j2 + 1] = cvtpk_bf16(p23.x, p23.y);
      }

    // O += P @ V  (K=32, pi-permuted key order on both operands)
    __builtin_amdgcn_s_setprio(1);
#pragma unroll
    for (int k2 = 0; k2 < 2; ++k2) {
      union { uint32_t u[4]; bf16x8 v; } pf[2];
#pragma unroll
      for (int qi = 0; qi < 2; ++qi)
#pragma unroll
        for (int j = 0; j < 4; ++j) pf[qi].u[j] = pw32[qi][k2][j];
#pragma unroll
      for (int nd = 0; nd < 4; ++nd) {
        const int row = nd * 16 + l16;  // d
        const bf16x8 vf = *(const bf16x8*)&sV_[row * 64 + (((k2 * 4 + quad) ^ (l16 & 7)) << 3)];
#pragma unroll
        for (int qi = 0; qi < 2; ++qi)
          oacc[qi][nd] = mfma16(pf[qi].v, vf, oacc[qi][nd]);
      }
    }
    __builtin_amdgcn_s_setprio(0);
  };

  // prologue: stage step 0 + full mask row, then drain.
  stage(0, 0);
  cp16(mfl + (size_t)b * SS + tid * 4, &sm[32768 + tid * 8]);   // 512 x 16B = 8KB
  __syncthreads();

  for (int w_ = 0; w_ < 16; ++w_) {
    if (w_ + 1 < 16) stage(w_ + 1, (w_ + 1) & 1);
    compute(w_, w_ & 1);
    __syncthreads();   // drains vmcnt: next chunk ready; protects parity buffer
  }

  // group-partial l per q row (sum over this group's keys)
  float lg[2];
#pragma unroll
  for (int qi = 0; qi < 2; ++qi) {
    float s = sum2[qi].x + sum2[qi].y;
    s += __shfl_xor(s, 16, 64);
    s += __shfl_xor(s, 32, 64);
    lg[qi] = s;   // uniform across quads; indexed by q=l16 within frag
  }

  // combine partials in LDS (K/V buffers + mask are dead now)
  float* sO = (float*)&sm[0];          // [128][stride 65] f32
  float* l0 = smask;                   // 128 floats
  if (grp == 0) {
#pragma unroll
    for (int qi = 0; qi < 2; ++qi)
#pragma unroll
      for (int nd = 0; nd < 4; ++nd)
#pragma unroll
        for (int e = 0; e < 4; ++e) {
          const int q = wl * 32 + qi * 16 + quad * 4 + e;
          sO[q * 65 + nd * 16 + l16] = oacc[qi][nd][e];
        }
    if (quad == 0) {
      l0[wl * 32 + l16] = lg[0];
      l0[wl * 32 + 16 + l16] = lg[1];
    }
  }
  __syncthreads();
  if (grp == 1) {
    float linv[2];
#pragma unroll
    for (int qi = 0; qi < 2; ++qi) {
      const float lt = l0[wl * 32 + qi * 16 + l16] + lg[qi];
      linv[qi] = lt > 0.f ? 1.0f / lt : 0.f;
    }
#pragma unroll
    for (int qi = 0; qi < 2; ++qi)
#pragma unroll
      for (int r = 0; r < 4; ++r) {
        const float li = __shfl(linv[qi], quad * 4 + r, 16);
        const int q = wl * 32 + qi * 16 + quad * 4 + r;
        const size_t row = (size_t)(b * SS + bqx * 128 + q) * EE + h * DD;
#pragma unroll
        for (int nd = 0; nd < 4; ++nd) {
          const int d = nd * 16 + l16;
          Oh[row + d] = f2bf((sO[q * 65 + d] + oacc[qi][nd][r]) * li);
        }
      }
  }
}

// ---------------- output projection: prefetch dbuf bf16, 128x64, BK=64 ------
// (R5 version, proven)
__global__ __launch_bounds__(256) void gemm_out(
    const u16* __restrict__ Ab, const u16* __restrict__ Bb,
    const float* __restrict__ bias, float* __restrict__ Cout) {
  __shared__ alignas(16) u16 sA[2][128 * 64];
  __shared__ alignas(16) u16 sB[2][64 * 64];
  // grid = (16, 32), 512 blocks = 8 XCDs x 64.
  const int flat = blockIdx.y * 16 + blockIdx.x;
  const int swz = (flat & 7) * 64 + (flat >> 3);
  const int bx = swz & 15, by = swz >> 4;

  const int rowBase = by * 128;
  const int colBase = bx * 64;
  const int tid = threadIdx.x;
  const int lane = tid & 63, w = tid >> 6;
  const int quad = lane >> 4, l16 = lane & 15;
  const int wr = w >> 1, wc = w & 1;

  size_t aSrc[4]; int aOff[4];
  size_t bSrc[2]; int bOff[2];
#pragma unroll
  for (int j = 0; j < 4; ++j) {
    const int c = tid + j * 256;
    const int row = c >> 3, sl = c & 7;
    aSrc[j] = (size_t)(rowBase + row) * KDIM + ((sl ^ (row & 7)) * 8);
    aOff[j] = c * 8;
  }
#pragma unroll
  for (int j = 0; j < 2; ++j) {
    const int c = tid + j * 256;
    const int row = c >> 3, sl = c & 7;
    bSrc[j] = (size_t)(colBase + row) * KDIM + ((sl ^ (row & 7)) * 8);
    bOff[j] = c * 8;
  }

  f32x4 acc[4][2];
#pragma unroll
  for (int mi = 0; mi < 4; ++mi)
#pragma unroll
    for (int ni = 0; ni < 2; ++ni)
#pragma unroll
      for (int e = 0; e < 4; ++e) acc[mi][ni][e] = 0.f;

  const int arow = wr * 64 + l16, brow = wc * 32 + l16;

  auto stage = [&](int k0, int bi) {
#pragma unroll
    for (int j = 0; j < 4; ++j) cp16(Ab + aSrc[j] + k0, &sA[bi][aOff[j]]);
#pragma unroll
    for (int j = 0; j < 2; ++j) cp16(Bb + bSrc[j] + k0, &sB[bi][bOff[j]]);
  };

  stage(0, 0);
  __syncthreads();
  int buf = 0;
  for (int k0 = 0; k0 < KDIM; k0 += 64) {
    if (k0 + 64 < KDIM) stage(k0 + 64, buf ^ 1);
    __builtin_amdgcn_s_setprio(1);
#pragma unroll
    for (int h = 0; h < 2; ++h) {
      bf16x8 af[4], bf[2];
#pragma unroll
      for (int i = 0; i < 4; ++i) {
        const int ar = arow + i * 16;
        af[i] = *(const bf16x8*)&sA[buf][ar * 64 + (((h * 4 + quad) ^ (ar & 7)) << 3)];
      }
#pragma unroll
      for (int i = 0; i < 2; ++i) {
        const int br = brow + i * 16;
        bf[i] = *(const bf16x8*)&sB[buf][br * 64 + (((h * 4 + quad) ^ (br & 7)) << 3)];
      }
#pragma unroll
      for (int mi = 0; mi < 4; ++mi)
#pragma unroll
        for (int ni = 0; ni < 2; ++ni)
          acc[mi][ni] = mfma16(af[mi], bf[ni], acc[mi][ni]);
    }
    __builtin_amdgcn_s_setprio(0);
    __syncthreads();
    buf ^= 1;
  }

#pragma unroll
  for (int mi = 0; mi < 4; ++mi) {
    const int rb = rowBase + wr * 64 + mi * 16 + quad * 4;
#pragma unroll
    for (int ni = 0; ni < 2; ++ni) {
      const int col = colBase + wc * 32 + ni * 16 + l16;
      const float bb = bias[col];
#pragma unroll
      for (int r = 0; r < 4; ++r)
        Cout[(size_t)(rb + r) * NDIM + col] = acc[mi][ni][r] + bb;
    }
  }
}

// ---------------- host launch ----------------
extern "C" void kernel_launch(void* const* d_in, const int* in_sizes, int n_in,
                              void* d_out, int out_size, void* d_ws, size_t ws_size,
                              hipStream_t stream) {
  const float* q    = (const float*)d_in[0];
  const float* k    = (const float*)d_in[1];
  const float* v    = (const float*)d_in[2];
  const int*   mask = (const int*)d_in[3];
  const float* Wq = (const float*)d_in[4];
  const float* bq = (const float*)d_in[5];
  const float* Wk = (const float*)d_in[6];
  const float* bk = (const float*)d_in[7];
  const float* Wv = (const float*)d_in[8];
  const float* bv = (const float*)d_in[9];
  const float* Wo = (const float*)d_in[10];
  const float* bo = (const float*)d_in[11];
  float* out = (float*)d_out;
  char* ws = (char*)d_ws;
  constexpr size_t MB = 1024 * 1024;
  u16* qb  = (u16*)(ws + 0 * MB);
  u16* kb  = (u16*)(ws + 8 * MB);
  u16* vb  = (u16*)(ws + 16 * MB);
  u16* wqb = (u16*)(ws + 24 * MB);
  u16* wkb = (u16*)(ws + 26 * MB);
  u16* wvb = (u16*)(ws + 28 * MB);
  u16* wob = (u16*)(ws + 30 * MB);
  u16* Qp  = (u16*)(ws + 32 * MB);
  u16* Kp  = (u16*)(ws + 40 * MB);
  u16* Vtg = (u16*)(ws + 48 * MB);   // V^T head-major, pi-permuted keys
  u16* oh  = (u16*)(ws + 56 * MB);
  float* csT = (float*)(ws + 64 * MB);   // [s][d] {cos,sin}, 1 MB
  // mask floats live in d_out: written by prep_cast, read by attn_kernel,
  // then gemm_out overwrites the whole output buffer afterwards. 16KB << 16MB.
  float* mfl = out;

  prep_cast<<<16384, 256, 0, stream>>>(q, k, v, Wq, Wk, Wv, Wo, mask,
                                       qb, kb, vb, wqb, wkb, wvb, wob, csT, mfl);
  gemm_qkv<<<dim3(8, 96), 256, 0, stream>>>(qb, kb, vb, wqb, wkb, wvb,
                                            bq, bk, bv, Qp, Kp, Vtg, csT);
  attn_kernel<<<dim3(16, 32), 512, 0, stream>>>(Qp, Kp, Vtg, mfl, oh);
  gemm_out<<<dim3(16, 32), 256, 0, stream>>>(oh, wob, bo, out);
}

// Round 12
// 214.766 us; speedup vs baseline: 1.1283x; 1.0195x over previous
//
#include <hip/hip_runtime.h>
#include <stdint.h>

typedef unsigned short u16;
typedef __bf16 bf16x8 __attribute__((ext_vector_type(8)));
typedef float f32x4 __attribute__((ext_vector_type(4)));
typedef float f32x2 __attribute__((ext_vector_type(2)));
typedef u16 u16x4v __attribute__((ext_vector_type(4)));

#define DI __device__ __forceinline__

constexpr int BB = 2, SS = 2048, EE = 1024, HH = 16, DD = 64;
constexpr int MROWS = BB * SS;   // 4096 tokens
constexpr int KDIM = 1024, NDIM = 1024;

constexpr float FM = 12.0f;      // fixed max offset (log2 domain)
constexpr float MNEG = -30000.f;

DI u16 f2bf(float f) {  // RNE float->bf16 (finite inputs)
  uint32_t u = __float_as_uint(f);
  return (u16)((u + 0x7FFFu + ((u >> 16) & 1u)) >> 16);
}
DI float bf2f(u16 h) { return __uint_as_float(((uint32_t)h) << 16); }

DI uint32_t cvtpk_bf16(float a, float b) {  // low=bf16(a), high=bf16(b), RNE
  uint32_t r;
  asm("v_cvt_pk_bf16_f32 %0, %1, %2" : "=v"(r) : "v"(a), "v"(b));
  return r;
}

DI void cp16(const void* g, void* lds) {
  __builtin_amdgcn_global_load_lds((const __attribute__((address_space(1))) void*)g,
                                   (__attribute__((address_space(3))) void*)lds, 16, 0, 0);
}

DI f32x4 mfma16(bf16x8 a, bf16x8 b, f32x4 c) {
  return __builtin_amdgcn_mfma_f32_16x16x32_bf16(a, b, c, 0, 0, 0);
}

// ---------------- prep: fp32 -> bf16 casts + RoPE table + mask floats -------
// rope/mask work rides along in the first 512 blocks (hidden under the
// memory-bound cast) -- saves a separate dispatch.
// csT layout: [d-group 16][s 2048][8 floats] = {c0 s0 c1 s1 c2 s2 c3 s3} for
// d = 4g..4g+3. The qkv epilogue reads per (s,4-aligned d0): lanes with
// consecutive s hit CONTIGUOUS 32B runs (fully coalesced; the old [s][d]
// layout gave 512B lane stride = 25% line utilization).
__global__ __launch_bounds__(256) void prep_cast(
    const float* __restrict__ q, const float* __restrict__ k, const float* __restrict__ v,
    const float* __restrict__ wq, const float* __restrict__ wk, const float* __restrict__ wv,
    const float* __restrict__ wo, const int* __restrict__ mask,
    u16* __restrict__ qb, u16* __restrict__ kb, u16* __restrict__ vb,
    u16* __restrict__ wqb, u16* __restrict__ wkb, u16* __restrict__ wvb,
    u16* __restrict__ wob, float* __restrict__ csT, float* __restrict__ mfl) {
  constexpr size_t SZI = (size_t)MROWS * EE;  // 4M
  constexpr size_t SZW = (size_t)EE * EE;     // 1M
  const int t = blockIdx.x * 256 + threadIdx.x;
  if (t < SS * 64) {   // RoPE table
    const int s = t >> 6, d = t & 63, j = d & 31;
    const float ang = (float)s * exp2f(-(float)j * 0.4152410118f);
    float2 cs; cs.x = cosf(ang); cs.y = sinf(ang);
    ((float2*)csT)[((d >> 2) << 13) + (s << 2) + (d & 3)] = cs;
    if (t < BB * SS) mfl[t] = mask[t] ? -FM : MNEG;
  }
  const size_t g = ((size_t)blockIdx.x * 256 + threadIdx.x) * 4;
  const float* src; u16* dst; size_t o;
  if (g < SZI)          { src = q; dst = qb; o = g; }
  else if (g < 2 * SZI) { src = k; dst = kb; o = g - SZI; }
  else if (g < 3 * SZI) { src = v; dst = vb; o = g - 2 * SZI; }
  else {
    size_t t2 = g - 3 * SZI;
    int wi = (int)(t2 / SZW);
    o = t2 - (size_t)(wi < 4 ? wi : 3) * SZW;   // wi==4 tail duplicates wo (benign)
    src = wi == 0 ? wq : wi == 1 ? wk : wi == 2 ? wv : wo;
    dst = wi == 0 ? wqb : wi == 1 ? wkb : wi == 2 ? wvb : wob;
  }
  const float4 f = *(const float4*)(src + o);
  u16x4v hv;
  hv[0] = f2bf(f.x); hv[1] = f2bf(f.y); hv[2] = f2bf(f.z); hv[3] = f2bf(f.w);
  *(u16x4v*)(dst + o) = hv;
}

// ---------------- QKV projection GEMM, BK=64, prefetch double-buffer --------
// Q/K: A = W (m=feat), B = X (n=token), RoPE in-register.
// V  : A = X (m=token), B = Wv (n=feat); Vtg keys pi-permuted in 32-groups.
__global__ __launch_bounds__(256) void gemm_qkv(
    const u16* __restrict__ qb, const u16* __restrict__ kb, const u16* __restrict__ vb,
    const u16* __restrict__ wqb, const u16* __restrict__ wkb, const u16* __restrict__ wvb,
    const float* __restrict__ bq, const float* __restrict__ bk, const float* __restrict__ bv,
    u16* __restrict__ Qp, u16* __restrict__ Kp, u16* __restrict__ Vtg,
    const float* __restrict__ csT) {
  __shared__ alignas(16) u16 sA[2][128 * 64];
  __shared__ alignas(16) u16 sB[2][128 * 64];
  // grid = (8, 96), 768 blocks = 8 XCDs x 96. hw id % 8 = XCD.
  const int flat = blockIdx.y * 8 + blockIdx.x;
  const int swz = (flat & 7) * 96 + (flat >> 3);
  const int bx = swz & 7, by = swz >> 3;   // by in [xcd*12, xcd*12+12)

  const int tsel = by >> 5;  // 0=Q 1=K 2=V
  const bool vtr = (tsel == 2);
  const u16* A    = tsel == 0 ? wqb : tsel == 1 ? wkb : vb;
  const u16* Bm   = tsel == 0 ? qb  : tsel == 1 ? kb  : wvb;
  const float* bias = tsel == 0 ? bq : tsel == 1 ? bk : bv;

  const int fBase = bx * 128;          // feature block (8)
  const int tBase = (by & 31) * 128;   // token block (32)
  const int aBase = vtr ? tBase : fBase;
  const int bBase = vtr ? fBase : tBase;
  const int tid = threadIdx.x;
  const int lane = tid & 63, w = tid >> 6;
  const int quad = lane >> 4, l16 = lane & 15;
  const int wr = w >> 1, wc = w & 1;

  size_t aSrc[4], bSrc[4];
  int dOff[4];
#pragma unroll
  for (int j = 0; j < 4; ++j) {
    const int c = tid + j * 256;
    const int row = c >> 3, sl = c & 7;
    const size_t off = (size_t)row * KDIM + ((sl ^ (row & 7)) * 8);
    aSrc[j] = (size_t)aBase * KDIM + off;
    bSrc[j] = (size_t)bBase * KDIM + off;
    dOff[j] = c * 8;
  }

  f32x4 acc[4][4];
#pragma unroll
  for (int mi = 0; mi < 4; ++mi)
#pragma unroll
    for (int ni = 0; ni < 4; ++ni)
#pragma unroll
      for (int e = 0; e < 4; ++e) acc[mi][ni][e] = 0.f;

  const int arow = wr * 64 + l16, brow = wc * 64 + l16;

  auto stage = [&](int k0, int bi) {
#pragma unroll
    for (int j = 0; j < 4; ++j) {
      cp16(A + aSrc[j] + k0, &sA[bi][dOff[j]]);
      cp16(Bm + bSrc[j] + k0, &sB[bi][dOff[j]]);
    }
  };

  stage(0, 0);
  __syncthreads();   // drains vmcnt(0): tile 0 resident
  int buf = 0;
  for (int k0 = 0; k0 < KDIM; k0 += 64) {
    if (k0 + 64 < KDIM) stage(k0 + 64, buf ^ 1);
    __builtin_amdgcn_s_setprio(1);
#pragma unroll
    for (int h = 0; h < 2; ++h) {
      bf16x8 af[4], bf[4];
#pragma unroll
      for (int i = 0; i < 4; ++i) {
        const int ar = arow + i * 16, br = brow + i * 16;
        af[i] = *(const bf16x8*)&sA[buf][ar * 64 + (((h * 4 + quad) ^ (ar & 7)) << 3)];
        bf[i] = *(const bf16x8*)&sB[buf][br * 64 + (((h * 4 + quad) ^ (br & 7)) << 3)];
      }
#pragma unroll
      for (int mi = 0; mi < 4; ++mi)
#pragma unroll
        for (int ni = 0; ni < 4; ++ni)
          acc[mi][ni] = mfma16(af[mi], bf[ni], acc[mi][ni]);
    }
    __builtin_amdgcn_s_setprio(0);
    __syncthreads();   // drains vmcnt: next tile ready; protects buf for restage
    buf ^= 1;
  }

  if (!vtr) {
    // Q/K epilogue: rows = feats, lanes = tokens. RoPE in-register.
    u16* C = tsel == 0 ? Qp : Kp;
#pragma unroll
    for (int mi = 0; mi < 4; ++mi) {
      const int fm = fBase + wr * 64 + mi * 16 + quad * 4;   // 4-aligned feat
      const float4 b4 = *(const float4*)&bias[fm];
      const int d0 = fm & 63;
      const float* csg = csT + ((size_t)(d0 >> 2) << 14);   // plane base
#pragma unroll
      for (int ni = 0; ni < 4; ++ni) {
        const int t = tBase + wc * 64 + ni * 16 + l16;
        const int srow = t & (SS - 1);
        const float* cs = csg + (srow << 3);   // contiguous 32B per lane
        const float4 cs01 = *(const float4*)cs;        // c0 s0 c1 s1
        const float4 cs23 = *(const float4*)(cs + 4);  // c2 s2 c3 s3
        const float v0 = acc[mi][ni][0] + b4.x;
        const float v1 = acc[mi][ni][1] + b4.y;
        const float v2 = acc[mi][ni][2] + b4.z;
        const float v3 = acc[mi][ni][3] + b4.w;
        const float o0 = v0 * cs01.x - v1 * cs01.y;
        const float o1 = v1 * cs01.z + v0 * cs01.w;
        const float o2 = v2 * cs23.x - v3 * cs23.y;
        const float o3 = v3 * cs23.z + v2 * cs23.w;
        uint2 pk;
        pk.x = cvtpk_bf16(o0, o1);
        pk.y = cvtpk_bf16(o2, o3);
        *(uint2*)&C[(size_t)t * NDIM + fm] = pk;
      }
    }
  } else {
    // V epilogue: rows = tokens (4-aligned -> 4 consecutive sp), lanes = feats.
#pragma unroll
    for (int ni = 0; ni < 4; ++ni) {
      const int f = fBase + wc * 64 + ni * 16 + l16;
      const int h = f >> 6, d = f & 63;
      const float bb = bias[f];
#pragma unroll
      for (int mi = 0; mi < 4; ++mi) {
        const int t0 = tBase + wr * 64 + mi * 16 + quad * 4;
        const int b = t0 >> 11, s0 = t0 & (SS - 1);
        const int sp0 = (s0 & ~31) | (((s0 >> 2) & 3) << 3) | (((s0 >> 4) & 1) << 2);
        uint2 pk;
        pk.x = cvtpk_bf16(acc[mi][ni][0] + bb, acc[mi][ni][1] + bb);
        pk.y = cvtpk_bf16(acc[mi][ni][2] + bb, acc[mi][ni][3] + bb);
        *(uint2*)&Vtg[((size_t)((b * 16 + h) * 64 + d)) * SS + sp0] = pk;
      }
    }
  }
}

// ---------------- flash attention: split-K wave groups (R5, proven) ---------
// 512 thr = 8 waves = 2 key-groups x 4 waves. Both groups cover the same 128
// q-rows (32/wave, 2 frags -> every ds_read feeds 2 MFMAs); group g handles
// 64-key chunk of each step. Fixed-max softmax => partial (O,l) combine by
// plain addition in LDS at the end. 72KB LDS, 2 blocks/CU -> 16 waves/CU.
__global__ __launch_bounds__(512, 4) void attn_kernel(
    const u16* __restrict__ Qp, const u16* __restrict__ Kp, const u16* __restrict__ Vtg,
    const float* __restrict__ mfl, u16* __restrict__ Oh) {
  // layout (u16 idx): grp g: K[bi] at g*16384 + bi*4096, V[bi] at g*16384+8192+bi*4096
  // mask floats at u16 32768 (8KB). Epilogue overlays: sO f32 over [0..], l0 over mask.
  __shared__ alignas(16) u16 sm[36864];   // 72 KB
  // grid = (16, 32), 512 blocks = 8 XCDs x 64.
  const int flat = blockIdx.y * 16 + blockIdx.x;
  const int swz = (flat & 7) * 64 + (flat >> 3);
  const int bqx = swz & 15, bh = swz >> 4;   // bh in [xcd*4, xcd*4+4)

  const int tid = threadIdx.x, lane = tid & 63, w = tid >> 6;
  const int quad = lane >> 4, l16 = lane & 15;
  const int b = bh >> 4, h = bh & 15;
  const int q0 = bqx * 128 + (w & 3) * 32;   // wave owns 32 q rows
  const int grp = w >> 2, wl = w & 3;
  const u16* Qb = Qp + (size_t)b * SS * EE + h * DD;
  const u16* Kb = Kp + (size_t)b * SS * EE + h * DD;
  const u16* Vb = Vtg + (size_t)bh * DD * SS;
  constexpr float C1 = 0.18033688011112042f;   // (1/sqrt(64)) * log2(e)
  float* smask = (float*)&sm[32768];

  bf16x8 qf[2][2];   // [q-frag][ks]
#pragma unroll
  for (int qi = 0; qi < 2; ++qi)
#pragma unroll
    for (int ks = 0; ks < 2; ++ks)
      qf[qi][ks] = *(const bf16x8*)(Qb + (size_t)(q0 + qi * 16 + l16) * EE + ks * 32 + quad * 8);

  f32x4 oacc[2][4];
#pragma unroll
  for (int qi = 0; qi < 2; ++qi)
#pragma unroll
    for (int nd = 0; nd < 4; ++nd)
#pragma unroll
      for (int e = 0; e < 4; ++e) oacc[qi][nd][e] = 0.f;
  f32x2 sum2[2];
  sum2[0] = {0.f, 0.f}; sum2[1] = {0.f, 0.f};

  const int gtid = tid & 255;   // thread within group

  // -------- stage this group's 64-key chunk of step w_ into buffer bi ------
  auto stage = [&](int w_, int bi) {
    const int key0 = w_ * 128 + grp * 64;
    u16* dK = &sm[grp * 16384 + bi * 4096];
    u16* dV = &sm[grp * 16384 + 8192 + bi * 4096];
#pragma unroll
    for (int i = 0; i < 2; ++i) {
      const int c = i * 256 + gtid;          // 512 chunks of 16B (8KB)
      const int key = c >> 3, sl = c & 7;
      cp16(Kb + (size_t)(key0 + key) * EE + ((sl ^ (key & 7)) * 8), &dK[c * 8]);
    }
#pragma unroll
    for (int i = 0; i < 2; ++i) {
      const int c = i * 256 + gtid;
      const int d = c >> 3, sl = c & 7;
      cp16(Vb + (size_t)d * SS + key0 + ((sl ^ (d & 7)) * 8), &dV[c * 8]);
    }
  };

  // -------- compute this group's 64-key chunk of step w_ from buffer bi ----
  auto compute = [&](int w_, int bi) {
    const int key0 = w_ * 128 + grp * 64;
    const u16* sK_ = &sm[grp * 16384 + bi * 4096];
    const u16* sV_ = &sm[grp * 16384 + 8192 + bi * 4096];
    // S^T = K * Q^T : D[m=key][n=q], per q-frag
    f32x4 sacc[2][4];
#pragma unroll
    for (int qi = 0; qi < 2; ++qi)
#pragma unroll
      for (int ni = 0; ni < 4; ++ni)
#pragma unroll
        for (int e = 0; e < 4; ++e) sacc[qi][ni][e] = 0.f;
    __builtin_amdgcn_s_setprio(1);
#pragma unroll
    for (int ks = 0; ks < 2; ++ks)
#pragma unroll
      for (int ni = 0; ni < 4; ++ni) {
        const int row = ni * 16 + l16;  // key
        const bf16x8 kf = *(const bf16x8*)&sK_[row * 64 + (((ks * 4 + quad) ^ (l16 & 7)) << 3)];
#pragma unroll
        for (int qi = 0; qi < 2; ++qi)
          sacc[qi][ni] = mfma16(kf, qf[qi][ks], sacc[qi][ni]);
      }
    __builtin_amdgcn_s_setprio(0);

    // hoisted mask loads: same values for both q-frags (was 2x the LDS reads)
    f32x2 mh01[4], mh23[4];
#pragma unroll
    for (int ni = 0; ni < 4; ++ni) {
      const int kb4 = key0 + ni * 16 + quad * 4;
      mh01[ni] = *(const f32x2*)&smask[kb4];
      mh23[ni] = *(const f32x2*)&smask[kb4 + 2];
    }

    // single-pass softmax: p = exp2(s*C1 + mval); raw v_exp_f32.
    uint32_t pw32[2][2][4];
#pragma unroll
    for (int qi = 0; qi < 2; ++qi)
#pragma unroll
      for (int ni = 0; ni < 4; ++ni) {
        f32x2 t01, t23;
        t01.x = sacc[qi][ni][0]; t01.y = sacc[qi][ni][1];
        t23.x = sacc[qi][ni][2]; t23.y = sacc[qi][ni][3];
        t01 = t01 * C1 + mh01[ni];
        t23 = t23 * C1 + mh23[ni];
        f32x2 p01, p23;
        p01.x = __builtin_amdgcn_exp2f(t01.x); p01.y = __builtin_amdgcn_exp2f(t01.y);
        p23.x = __builtin_amdgcn_exp2f(t23.x); p23.y = __builtin_amdgcn_exp2f(t23.y);
        sum2[qi] += p01;
        sum2[qi] += p23;
        const int k2 = ni >> 1, j2 = (ni & 1) * 2;
        pw32[qi][k2][j2]     = cvtpk_bf16(p01.x, p01.y);
        pw32[qi][k2][j2 + 1] = cvtpk_bf16(p23.x, p23.y);
      }

    // O += P @ V  (K=32, pi-permuted key order on both operands)
    __builtin_amdgcn_s_setprio(1);
#pragma unroll
    for (int k2 = 0; k2 < 2; ++k2) {
      union { uint32_t u[4]; bf16x8 v; } pf[2];
#pragma unroll
      for (int qi = 0; qi < 2; ++qi)
#pragma unroll
        for (int j = 0; j < 4; ++j) pf[qi].u[j] = pw32[qi][k2][j];
#pragma unroll
      for (int nd = 0; nd < 4; ++nd) {
        const int row = nd * 16 + l16;  // d
        const bf16x8 vf = *(const bf16x8*)&sV_[row * 64 + (((k2 * 4 + quad) ^ (l16 & 7)) << 3)];
#pragma unroll
        for (int qi = 0; qi < 2; ++qi)
          oacc[qi][nd] = mfma16(pf[qi].v, vf, oacc[qi][nd]);
      }
    }
    __builtin_amdgcn_s_setprio(0);
  };

  // prologue: stage step 0 + full mask row, then drain.
  stage(0, 0);
  cp16(mfl + (size_t)b * SS + tid * 4, &sm[32768 + tid * 8]);   // 512 x 16B = 8KB
  __syncthreads();

  for (int w_ = 0; w_ < 16; ++w_) {
    if (w_ + 1 < 16) stage(w_ + 1, (w_ + 1) & 1);
    compute(w_, w_ & 1);
    __syncthreads();   // drains vmcnt: next chunk ready; protects parity buffer
  }

  // group-partial l per q row (sum over this group's keys)
  float lg[2];
#pragma unroll
  for (int qi = 0; qi < 2; ++qi) {
    float s = sum2[qi].x + sum2[qi].y;
    s += __shfl_xor(s, 16, 64);
    s += __shfl_xor(s, 32, 64);
    lg[qi] = s;   // uniform across quads; indexed by q=l16 within frag
  }

  // combine partials in LDS (K/V buffers + mask are dead now)
  float* sO = (float*)&sm[0];          // [128][stride 65] f32
  float* l0 = smask;                   // 128 floats
  if (grp == 0) {
#pragma unroll
    for (int qi = 0; qi < 2; ++qi)
#pragma unroll
      for (int nd = 0; nd < 4; ++nd)
#pragma unroll
        for (int e = 0; e < 4; ++e) {
          const int q = wl * 32 + qi * 16 + quad * 4 + e;
          sO[q * 65 + nd * 16 + l16] = oacc[qi][nd][e];
        }
    if (quad == 0) {
      l0[wl * 32 + l16] = lg[0];
      l0[wl * 32 + 16 + l16] = lg[1];
    }
  }
  __syncthreads();
  if (grp == 1) {
    float linv[2];
#pragma unroll
    for (int qi = 0; qi < 2; ++qi) {
      const float lt = l0[wl * 32 + qi * 16 + l16] + lg[qi];
      linv[qi] = lt > 0.f ? 1.0f / lt : 0.f;
    }
#pragma unroll
    for (int qi = 0; qi < 2; ++qi)
#pragma unroll
      for (int r = 0; r < 4; ++r) {
        const float li = __shfl(linv[qi], quad * 4 + r, 16);
        const int q = wl * 32 + qi * 16 + quad * 4 + r;
        const size_t row = (size_t)(b * SS + bqx * 128 + q) * EE + h * DD;
#pragma unroll
        for (int nd = 0; nd < 4; ++nd) {
          const int d = nd * 16 + l16;
          Oh[row + d] = f2bf((sO[q * 65 + d] + oacc[qi][nd][r]) * li);
        }
      }
  }
}

// ---------------- output projection: prefetch dbuf bf16, 128x64, BK=64 ------
// (R5 version, proven)
__global__ __launch_bounds__(256) void gemm_out(
    const u16* __restrict__ Ab, const u16* __restrict__ Bb,
    const float* __restrict__ bias, float* __restrict__ Cout) {
  __shared__ alignas(16) u16 sA[2][128 * 64];
  __shared__ alignas(16) u16 sB[2][64 * 64];
  // grid = (16, 32), 512 blocks = 8 XCDs x 64.
  const int flat = blockIdx.y * 16 + blockIdx.x;
  const int swz = (flat & 7) * 64 + (flat >> 3);
  const int bx = swz & 15, by = swz >> 4;

  const int rowBase = by * 128;
  const int colBase = bx * 64;
  const int tid = threadIdx.x;
  const int lane = tid & 63, w = tid >> 6;
  const int quad = lane >> 4, l16 = lane & 15;
  const int wr = w >> 1, wc = w & 1;

  size_t aSrc[4]; int aOff[4];
  size_t bSrc[2]; int bOff[2];
#pragma unroll
  for (int j = 0; j < 4; ++j) {
    const int c = tid + j * 256;
    const int row = c >> 3, sl = c & 7;
    aSrc[j] = (size_t)(rowBase + row) * KDIM + ((sl ^ (row & 7)) * 8);
    aOff[j] = c * 8;
  }
#pragma unroll
  for (int j = 0; j < 2; ++j) {
    const int c = tid + j * 256;
    const int row = c >> 3, sl = c & 7;
    bSrc[j] = (size_t)(colBase + row) * KDIM + ((sl ^ (row & 7)) * 8);
    bOff[j] = c * 8;
  }

  f32x4 acc[4][2];
#pragma unroll
  for (int mi = 0; mi < 4; ++mi)
#pragma unroll
    for (int ni = 0; ni < 2; ++ni)
#pragma unroll
      for (int e = 0; e < 4; ++e) acc[mi][ni][e] = 0.f;

  const int arow = wr * 64 + l16, brow = wc * 32 + l16;

  auto stage = [&](int k0, int bi) {
#pragma unroll
    for (int j = 0; j < 4; ++j) cp16(Ab + aSrc[j] + k0, &sA[bi][aOff[j]]);
#pragma unroll
    for (int j = 0; j < 2; ++j) cp16(Bb + bSrc[j] + k0, &sB[bi][bOff[j]]);
  };

  stage(0, 0);
  __syncthreads();
  int buf = 0;
  for (int k0 = 0; k0 < KDIM; k0 += 64) {
    if (k0 + 64 < KDIM) stage(k0 + 64, buf ^ 1);
    __builtin_amdgcn_s_setprio(1);
#pragma unroll
    for (int h = 0; h < 2; ++h) {
      bf16x8 af[4], bf[2];
#pragma unroll
      for (int i = 0; i < 4; ++i) {
        const int ar = arow + i * 16;
        af[i] = *(const bf16x8*)&sA[buf][ar * 64 + (((h * 4 + quad) ^ (ar & 7)) << 3)];
      }
#pragma unroll
      for (int i = 0; i < 2; ++i) {
        const int br = brow + i * 16;
        bf[i] = *(const bf16x8*)&sB[buf][br * 64 + (((h * 4 + quad) ^ (br & 7)) << 3)];
      }
#pragma unroll
      for (int mi = 0; mi < 4; ++mi)
#pragma unroll
        for (int ni = 0; ni < 2; ++ni)
          acc[mi][ni] = mfma16(af[mi], bf[ni], acc[mi][ni]);
    }
    __builtin_amdgcn_s_setprio(0);
    __syncthreads();
    buf ^= 1;
  }

#pragma unroll
  for (int mi = 0; mi < 4; ++mi) {
    const int rb = rowBase + wr * 64 + mi * 16 + quad * 4;
#pragma unroll
    for (int ni = 0; ni < 2; ++ni) {
      const int col = colBase + wc * 32 + ni * 16 + l16;
      const float bb = bias[col];
#pragma unroll
      for (int r = 0; r < 4; ++r)
        Cout[(size_t)(rb + r) * NDIM + col] = acc[mi][ni][r] + bb;
    }
  }
}

// ---------------- host launch ----------------
extern "C" void kernel_launch(void* const* d_in, const int* in_sizes, int n_in,
                              void* d_out, int out_size, void* d_ws, size_t ws_size,
                              hipStream_t stream) {
  const float* q    = (const float*)d_in[0];
  const float* k    = (const float*)d_in[1];
  const float* v    = (const float*)d_in[2];
  const int*   mask = (const int*)d_in[3];
  const float* Wq = (const float*)d_in[4];
  const float* bq = (const float*)d_in[5];
  const float* Wk = (const float*)d_in[6];
  const float* bk = (const float*)d_in[7];
  const float* Wv = (const float*)d_in[8];
  const float* bv = (const float*)d_in[9];
  const float* Wo = (const float*)d_in[10];
  const float* bo = (const float*)d_in[11];
  float* out = (float*)d_out;
  char* ws = (char*)d_ws;
  constexpr size_t MB = 1024 * 1024;
  u16* qb  = (u16*)(ws + 0 * MB);
  u16* kb  = (u16*)(ws + 8 * MB);
  u16* vb  = (u16*)(ws + 16 * MB);
  u16* wqb = (u16*)(ws + 24 * MB);
  u16* wkb = (u16*)(ws + 26 * MB);
  u16* wvb = (u16*)(ws + 28 * MB);
  u16* wob = (u16*)(ws + 30 * MB);
  u16* Qp  = (u16*)(ws + 32 * MB);
  u16* Kp  = (u16*)(ws + 40 * MB);
  u16* Vtg = (u16*)(ws + 48 * MB);   // V^T head-major, pi-permuted keys
  u16* oh  = (u16*)(ws + 56 * MB);
  float* csT = (float*)(ws + 64 * MB);   // [d-grp 16][s 2048][8], 1 MB
  // mask floats live in d_out: written by prep_cast, read by attn_kernel,
  // then gemm_out overwrites the whole output buffer afterwards. 16KB << 16MB.
  float* mfl = out;

  prep_cast<<<16384, 256, 0, stream>>>(q, k, v, Wq, Wk, Wv, Wo, mask,
                                       qb, kb, vb, wqb, wkb, wvb, wob, csT, mfl);
  gemm_qkv<<<dim3(8, 96), 256, 0, stream>>>(qb, kb, vb, wqb, wkb, wvb,
                                            bq, bk, bv, Qp, Kp, Vtg, csT);
  attn_kernel<<<dim3(16, 32), 512, 0, stream>>>(Qp, Kp, Vtg, mfl, oh);
  gemm_out<<<dim3(16, 32), 256, 0, stream>>>(oh, wob, bo, out);
}